// Round 20
// baseline (355.007 us; speedup 1.0000x reference)
//
#include <hip/hip_runtime.h>
#include <hip/hip_bf16.h>

#define S_LEN 4096
#define DMODEL 64
#define QBLK 256                            // per block (4 waves x 64 rows)
#define NQT (S_LEN / QBLK)                  // 16 q-tiles
#define KBLK 32
#define NKT (S_LEN / KBLK)                  // 128 k-tiles
#define NSPLIT 8
#define NROWS ((size_t)8 * S_LEN)           // 32768 (b,q) rows
#define NELEM ((size_t)8 * S_LEN * DMODEL)  // per-tensor elements (Q/K/V)
#define TSZ 2048                            // elements per staging sub-tile (4KB bf16)
#define MH 2048                             // mask bytes per (kt,h) sub-tile (u8)
#define QSCALE 0.180336880f                 // 0.125 * log2(e)

typedef __attribute__((ext_vector_type(8))) short bf16x8;
typedef __attribute__((ext_vector_type(4))) float f32x4;
typedef __attribute__((ext_vector_type(4))) unsigned short us4;
typedef __attribute__((ext_vector_type(8))) unsigned short us8;
typedef __attribute__((ext_vector_type(4))) unsigned int u32x4;

// barrier without the vmcnt(0) drain (LDS visibility needs only lgkmcnt)
#define LDS_BARRIER()                                            \
    do {                                                         \
        asm volatile("s_waitcnt lgkmcnt(0)" ::: "memory");       \
        __builtin_amdgcn_s_barrier();                            \
    } while (0)

__device__ __forceinline__ float bf2f(unsigned short u) {
    unsigned int x = ((unsigned int)u) << 16;
    return __builtin_bit_cast(float, x);
}
__device__ __forceinline__ unsigned short f2bf(float f) {
    unsigned int u = __builtin_bit_cast(unsigned int, f);
    u += 0x7FFFu + ((u >> 16) & 1u);   // RNE
    return (unsigned short)(u >> 16);
}
__device__ __forceinline__ unsigned int packbf2(float lo, float hi) {
    __hip_bfloat162 h = __float22bfloat162_rn(float2{lo, hi});
    unsigned int w;
    __builtin_memcpy(&w, &h, sizeof(w));
    return w;
}
// byte i of word w as float (v_cvt_f32_ubyte)
__device__ __forceinline__ float ub(unsigned int w, int i) {
    return (float)((w >> (8 * i)) & 0xFFu);
}
__device__ __forceinline__ bf16x8 cvt8s(const float* __restrict__ p, float c) {
    f32x4 a = *(const f32x4*)p;
    f32x4 b = *(const f32x4*)(p + 4);
    bf16x8 r;
    r[0] = (short)f2bf(a[0] * c); r[1] = (short)f2bf(a[1] * c);
    r[2] = (short)f2bf(a[2] * c); r[3] = (short)f2bf(a[3] * c);
    r[4] = (short)f2bf(b[0] * c); r[5] = (short)f2bf(b[1] * c);
    r[6] = (short)f2bf(b[2] * c); r[7] = (short)f2bf(b[3] * c);
    return r;
}
__device__ __forceinline__ unsigned int q8(float m) {
    return (unsigned int)(m * 255.f + 0.5f);   // m in [0,1)
}

// ---- fused converts. blocks [0,1024): K, [1024,2048): V, [2048,10240): M(u8) ----
__global__ __launch_bounds__(256)
void convert_all(const float* __restrict__ K, const float* __restrict__ V,
                 const float* __restrict__ M,
                 unsigned short* __restrict__ Ktt, unsigned short* __restrict__ Vtt,
                 unsigned char* __restrict__ Mu) {
    const int t = threadIdx.x;
    int bid = blockIdx.x;

    if (bid < 1024) {
        // K -> fragment-major Ktt[b][kt][frag][lane]
        const int b  = bid >> 7;
        const int kt = bid & 127;
        const int l = t & 63, frag = t >> 6;
        const int j = l & 15, g = l >> 4;
        const int row = kt * KBLK + ((frag >> 1) & 1) * 16 + j;
        const int col = (frag & 1) * 32 + g * 8;
        const float* src = K + ((size_t)b * S_LEN + row) * DMODEL + col;
        f32x4 a = *(const f32x4*)src;
        f32x4 c = *(const f32x4*)(src + 4);
        us8 o;
        o[0] = f2bf(a[0]); o[1] = f2bf(a[1]); o[2] = f2bf(a[2]); o[3] = f2bf(a[3]);
        o[4] = f2bf(c[0]); o[5] = f2bf(c[1]); o[6] = f2bf(c[2]); o[7] = f2bf(c[3]);
        *(us8*)(Ktt + ((size_t)(b * NKT + kt)) * TSZ + t * 8) = o;
    } else if (bid < 2048) {
        // V -> fragment-major Vtt[b][kt][dt][lane] (transpose via LDS)
        bid -= 1024;
        __shared__ unsigned short lk[KBLK][68];
        const int b  = bid >> 7;
        const int kt = bid & 127;
        {
            const int key = t >> 3, d0 = (t & 7) * 8;
            const float* src = V + ((size_t)b * S_LEN + kt * KBLK + key) * DMODEL + d0;
            f32x4 a = *(const f32x4*)src;
            f32x4 c = *(const f32x4*)(src + 4);
            lk[key][d0 + 0] = f2bf(a[0]); lk[key][d0 + 1] = f2bf(a[1]);
            lk[key][d0 + 2] = f2bf(a[2]); lk[key][d0 + 3] = f2bf(a[3]);
            lk[key][d0 + 4] = f2bf(c[0]); lk[key][d0 + 5] = f2bf(c[1]);
            lk[key][d0 + 6] = f2bf(c[2]); lk[key][d0 + 7] = f2bf(c[3]);
        }
        __syncthreads();
        {
            const int l = t & 63, dt = t >> 6;
            const int j = l & 15, g = l >> 4;
            us8 o;
            #pragma unroll
            for (int e = 0; e < 8; ++e) {
                const int key = 16 * (e >> 2) + 4 * g + (e & 3);
                o[e] = lk[key][dt * 16 + j];
            }
            *(us8*)(Vtt + ((size_t)(b * NKT + kt)) * TSZ + t * 8) = o;
        }
    } else {
        // M -> per-wave-linear u8 Mu[qt][kt][h=0..3][t*8..]; 255-scale cancels in renorm
        bid -= 2048;                         // [0, 8192)
        const int qt  = bid >> 9;            // 0..15
        const int rem = bid & 511;
        const int kt  = rem >> 2;            // 0..127
        const int h   = rem & 3;             // q-subgroup (16 rows each)
        const int l = t & 63, w = t >> 6;
        const int j = l & 15, g = l >> 4;
        const int row = qt * QBLK + w * 64 + h * 16 + j;
        const float* src = M + ((size_t)row) * S_LEN + kt * KBLK;
        f32x4 a = *(const f32x4*)(src + 4 * g);
        f32x4 c = *(const f32x4*)(src + 16 + 4 * g);
        uint2 o;
        o.x = q8(a[0]) | (q8(a[1]) << 8) | (q8(a[2]) << 16) | (q8(a[3]) << 24);
        o.y = q8(c[0]) | (q8(c[1]) << 8) | (q8(c[2]) << 16) | (q8(c[3]) << 24);
        *(uint2*)(Mu + (((size_t)(qt * NKT + kt)) * 4 + h) * MH + t * 8) = o;
    }
}

// ---- attention: 64 q-rows/wave (4 chains), LDS dbuf, split-K=8, bf16 partials ----
template <int SPLITS>
__global__ __launch_bounds__(256, 4)
void attn_frag(const float* __restrict__ Q,
               const unsigned short* __restrict__ Ktt,
               const unsigned short* __restrict__ Vtt,
               const unsigned char* __restrict__ Mu,
               unsigned short* __restrict__ Pacc, float* __restrict__ Plsum,
               float* __restrict__ O) {
    // S: K buf0 [0,2048), K buf1 [2048,4096), V buf0 [4096,6144), V buf1 [6144,8192)
    __shared__ __align__(16) unsigned short S[8192];   // 16 KB

    const int t    = threadIdx.x;
    const int wave = t >> 6;
    const int l    = t & 63;
    const int g    = l >> 4;
    const int j    = l & 15;

    const int bid = blockIdx.x;
    const int b   = bid & 7;             // batch <-> XCD (K/V L2-resident)
    const int qt  = (bid >> 3) & 15;
    const int sp  = (SPLITS > 1) ? (bid >> 7) : 0;
    const int nsteps = NKT / SPLITS;
    const int qrow0 = qt * QBLK + wave * 64 + j;   // chain c: qrow0 + 16*c
    const size_t row0 = (size_t)b * S_LEN + qrow0;

    const float* Qb = Q + (size_t)b * S_LEN * DMODEL;
    bf16x8 qf0[4], qf1[4];
    #pragma unroll
    for (int c = 0; c < 4; ++c) {
        qf0[c] = cvt8s(Qb + (size_t)(qrow0 + 16 * c) * DMODEL + g * 8, QSCALE);
        qf1[c] = cvt8s(Qb + (size_t)(qrow0 + 16 * c) * DMODEL + g * 8 + 32, QSCALE);
    }

    bf16x8 vones;
    #pragma unroll
    for (int e = 0; e < 8; ++e) vones[e] = (short)0x3F80;

    f32x4 acc[4][4];     // [chain][dt]
    f32x4 accl[4];       // [chain]
    #pragma unroll
    for (int c = 0; c < 4; ++c) {
        accl[c] = f32x4{0.f, 0.f, 0.f, 0.f};
        #pragma unroll
        for (int dt = 0; dt < 4; ++dt) acc[c][dt] = f32x4{0.f, 0.f, 0.f, 0.f};
    }

    const int kt0 = sp * nsteps;
    const unsigned short* pk = Ktt + (size_t)(b * NKT + kt0) * TSZ + t * 8;
    const unsigned short* pv = Vtt + (size_t)(b * NKT + kt0) * TSZ + t * 8;
    const unsigned char*  pm = Mu + ((size_t)(qt * NKT + kt0) * 4) * MH + t * 8;

    // ---- prologue: tile kt0 -> buf0; tile kt0+1 -> regs; masks for both ----
    us8 kreg = *(const us8*)pk;
    us8 vreg = *(const us8*)pv;
    uint2 mA[4], mB[4];
    #pragma unroll
    for (int c = 0; c < 4; ++c) mA[c] = *(const uint2*)(pm + c * MH);
    *(us8*)&S[t * 8]        = kreg;
    *(us8*)&S[4096 + t * 8] = vreg;
    kreg = *(const us8*)(pk + TSZ);
    vreg = *(const us8*)(pv + TSZ);
    #pragma unroll
    for (int c = 0; c < 4; ++c) mB[c] = *(const uint2*)(pm + (4 + c) * MH);
    pk += 2 * TSZ; pv += 2 * TSZ; pm += 8 * MH;   // -> tile s+2
    LDS_BARRIER();

    // Prefetch pointers overrun the split range by <=2 tiles at the end; those
    // reads land in the adjacent ws arrays (in-bounds) and are never consumed.
    for (int p = 0; p < nsteps / 2; ++p) {
        #pragma unroll
        for (int u = 0; u < 2; ++u) {
            // 1) stage tile s+1 (in regs) into buf u^1 — linear t*16, conflict-free
            *(us8*)&S[(u ^ 1) * 2048 + t * 8]        = kreg;
            *(us8*)&S[4096 + (u ^ 1) * 2048 + t * 8] = vreg;

            // 2) issue loads for tile s+2
            kreg = *(const us8*)pk; pk += TSZ;
            vreg = *(const us8*)pv; pv += TSZ;

            // 3) compute step s from buf u (static offsets via unroll)
            bf16x8 kf0 = *(const bf16x8*)&S[u * 2048 + 0 * 512 + l * 8];
            bf16x8 kf1 = *(const bf16x8*)&S[u * 2048 + 1 * 512 + l * 8];
            bf16x8 kf2 = *(const bf16x8*)&S[u * 2048 + 2 * 512 + l * 8];
            bf16x8 kf3 = *(const bf16x8*)&S[u * 2048 + 3 * 512 + l * 8];

            bf16x8 pf[4];
            #pragma unroll
            for (int c = 0; c < 4; ++c) {
                f32x4 s0 = {0.f, 0.f, 0.f, 0.f}, s1 = {0.f, 0.f, 0.f, 0.f};
                s0 = __builtin_amdgcn_mfma_f32_16x16x32_bf16(kf0, qf0[c], s0, 0, 0, 0);
                s0 = __builtin_amdgcn_mfma_f32_16x16x32_bf16(kf1, qf1[c], s0, 0, 0, 0);
                s1 = __builtin_amdgcn_mfma_f32_16x16x32_bf16(kf2, qf0[c], s1, 0, 0, 0);
                s1 = __builtin_amdgcn_mfma_f32_16x16x32_bf16(kf3, qf1[c], s1, 0, 0, 0);
                // s0[r]: key kb+4g+r; s1[r]: key kb+16+4g+r; col = qrow0+16c

                const uint2 m = u ? mB[c] : mA[c];
                float e0[4], e1[4];
                #pragma unroll
                for (int r = 0; r < 4; ++r) {
                    e0[r] = __builtin_amdgcn_exp2f(s0[r]) * ub(m.x, r);
                    e1[r] = __builtin_amdgcn_exp2f(s1[r]) * ub(m.y, r);
                }
                u32x4 pw;
                pw[0] = packbf2(e0[0], e0[1]); pw[1] = packbf2(e0[2], e0[3]);
                pw[2] = packbf2(e1[0], e1[1]); pw[3] = packbf2(e1[2], e1[3]);
                pf[c] = __builtin_bit_cast(bf16x8, pw);  // slot e: key kb+16*(e>>2)+4g+(e&3)

                accl[c] = __builtin_amdgcn_mfma_f32_16x16x32_bf16(vones, pf[c], accl[c], 0, 0, 0);
            }

            // 4) reload masks for step s+2 into the same (static) slots
            if (u == 0) {
                #pragma unroll
                for (int c = 0; c < 4; ++c) mA[c] = *(const uint2*)(pm + c * MH);
            } else {
                #pragma unroll
                for (int c = 0; c < 4; ++c) mB[c] = *(const uint2*)(pm + c * MH);
            }
            pm += 4 * MH;

            // 5) PV: each V fragment load feeds all 4 chains (4x amortized)
            #pragma unroll
            for (int dt = 0; dt < 4; ++dt) {
                bf16x8 vf = *(const bf16x8*)&S[4096 + u * 2048 + dt * 512 + l * 8];
                #pragma unroll
                for (int c = 0; c < 4; ++c)
                    acc[c][dt] = __builtin_amdgcn_mfma_f32_16x16x32_bf16(vf, pf[c], acc[c][dt], 0, 0, 0);
            }

            // 6) drain-free barrier
            LDS_BARRIER();
        }
    }

    if (SPLITS > 1) {
        // bf16 partials: rounding cancels in the final normalize (0.3% rel)
        #pragma unroll
        for (int c = 0; c < 4; ++c) {
            const size_t row = row0 + 16 * c;
            if (g == 0) Plsum[(size_t)sp * NROWS + row] = accl[c][0];
            unsigned short* pr = Pacc + ((size_t)sp * NROWS + row) * DMODEL;
            #pragma unroll
            for (int dt = 0; dt < 4; ++dt) {
                us4 o;
                #pragma unroll
                for (int r = 0; r < 4; ++r) o[r] = f2bf(acc[c][dt][r]);
                *(us4*)(pr + dt * 16 + g * 4) = o;
            }
        }
    } else {
        #pragma unroll
        for (int c = 0; c < 4; ++c) {
            const float inv = 1.0f / accl[c][0];
            float* orow = O + (row0 + 16 * c) * DMODEL;
            #pragma unroll
            for (int dt = 0; dt < 4; ++dt) {
                f32x4 o;
                #pragma unroll
                for (int r = 0; r < 4; ++r) o[r] = acc[c][dt][r] * inv;
                *(f32x4*)(orow + dt * 16 + g * 4) = o;
            }
        }
    }
}

// ---- reduce: O = sum_s acc_s(bf16) / sum_s lsum_s ----
template <int SPLITS>
__global__ __launch_bounds__(256)
void reduce_split(const unsigned short* __restrict__ Pacc,
                  const float* __restrict__ Plsum, float* __restrict__ O) {
    const int t = threadIdx.x;
    const size_t rid = (size_t)blockIdx.x * 16 + (t >> 4);
    const int seg = (t & 15) * 4;

    float ls = 0.f;
    f32x4 a = {0.f, 0.f, 0.f, 0.f};
    #pragma unroll
    for (int s = 0; s < SPLITS; ++s) {
        ls += Plsum[(size_t)s * NROWS + rid];
        us4 v = *(const us4*)(Pacc + ((size_t)s * NROWS + rid) * DMODEL + seg);
        a[0] += bf2f(v[0]); a[1] += bf2f(v[1]); a[2] += bf2f(v[2]); a[3] += bf2f(v[3]);
    }
    const float inv = 1.0f / ls;
    f32x4 o = {a[0] * inv, a[1] * inv, a[2] * inv, a[3] * inv};
    *(f32x4*)(O + rid * DMODEL + seg) = o;
}

// ---- no-workspace fallback: direct fp32 loads (validated math, QBLK=64 grid) ----
__global__ __launch_bounds__(256)
void attn_fb(const float* __restrict__ Q, const float* __restrict__ Kf,
             const float* __restrict__ Vf, const float* __restrict__ M,
             float* __restrict__ O) {
    const int t    = threadIdx.x;
    const int wave = t >> 6;
    const int lane = t & 63;
    const int g    = lane >> 4;
    const int j    = lane & 15;
    const int bid  = blockIdx.x;
    const int b    = bid & 7;
    const int qt   = bid >> 3;
    const int qrow = qt * 64 + wave * 16 + j;

    const float* Qb = Q + (size_t)b * S_LEN * DMODEL;
    const bf16x8 qf0 = cvt8s(Qb + (size_t)qrow * DMODEL + g * 8, QSCALE);
    const bf16x8 qf1 = cvt8s(Qb + (size_t)qrow * DMODEL + g * 8 + 32, QSCALE);

    f32x4 acc[4];
    #pragma unroll
    for (int dt = 0; dt < 4; ++dt) acc[dt] = f32x4{0.f, 0.f, 0.f, 0.f};
    float lsum = 0.f;

    const float* Kfb = Kf + (size_t)b * S_LEN * DMODEL;
    const float* Vfb = Vf + (size_t)b * S_LEN * DMODEL;
    const float* mrow = M + (size_t)qrow * S_LEN;

    int kg[8];
    #pragma unroll
    for (int e = 0; e < 8; ++e) kg[e] = 16 * (e >> 2) + 4 * g + (e & 3);

    for (int kt = 0; kt < NKT; ++kt) {
        const int kb = kt * KBLK;
        bf16x8 kf00 = cvt8s(Kfb + (size_t)(kb + j) * DMODEL + g * 8, 1.0f);
        bf16x8 kf01 = cvt8s(Kfb + (size_t)(kb + j) * DMODEL + g * 8 + 32, 1.0f);
        bf16x8 kf10 = cvt8s(Kfb + (size_t)(kb + 16 + j) * DMODEL + g * 8, 1.0f);
        bf16x8 kf11 = cvt8s(Kfb + (size_t)(kb + 16 + j) * DMODEL + g * 8 + 32, 1.0f);

        f32x4 st0 = {0.f, 0.f, 0.f, 0.f};
        f32x4 st1 = {0.f, 0.f, 0.f, 0.f};
        st0 = __builtin_amdgcn_mfma_f32_16x16x32_bf16(kf00, qf0, st0, 0, 0, 0);
        st0 = __builtin_amdgcn_mfma_f32_16x16x32_bf16(kf01, qf1, st0, 0, 0, 0);
        st1 = __builtin_amdgcn_mfma_f32_16x16x32_bf16(kf10, qf0, st1, 0, 0, 0);
        st1 = __builtin_amdgcn_mfma_f32_16x16x32_bf16(kf11, qf1, st1, 0, 0, 0);

        f32x4 m0 = *(const f32x4*)(mrow + kb + g * 4);
        f32x4 m1 = *(const f32x4*)(mrow + kb + 16 + g * 4);

        bf16x8 pf;
        #pragma unroll
        for (int r = 0; r < 4; ++r) {
            float w0 = __builtin_amdgcn_exp2f(st0[r]) * m0[r];
            float w1 = __builtin_amdgcn_exp2f(st1[r]) * m1[r];
            lsum += w0 + w1;
            pf[r]     = (short)f2bf(w0);
            pf[4 + r] = (short)f2bf(w1);
        }

        #pragma unroll
        for (int dt = 0; dt < 4; ++dt) {
            bf16x8 vf;
            #pragma unroll
            for (int e = 0; e < 8; ++e)
                vf[e] = (short)f2bf(Vfb[(size_t)(kb + kg[e]) * DMODEL + dt * 16 + j]);
            acc[dt] = __builtin_amdgcn_mfma_f32_16x16x32_bf16(vf, pf, acc[dt], 0, 0, 0);
        }
    }

    lsum += __shfl_xor(lsum, 16, 64);
    lsum += __shfl_xor(lsum, 32, 64);
    const float inv = 1.0f / lsum;

    float* orow = O + ((size_t)b * S_LEN + qrow) * DMODEL;
    #pragma unroll
    for (int dt = 0; dt < 4; ++dt) {
        f32x4 o;
        #pragma unroll
        for (int r = 0; r < 4; ++r) o[r] = acc[dt][r] * inv;
        *(f32x4*)(orow + dt * 16 + g * 4) = o;
    }
}

extern "C" void kernel_launch(void* const* d_in, const int* in_sizes, int n_in,
                              void* d_out, int out_size, void* d_ws, size_t ws_size,
                              hipStream_t stream) {
    const float* Q = (const float*)d_in[0];
    const float* K = (const float*)d_in[1];
    const float* V = (const float*)d_in[2];
    const float* M = (const float*)d_in[3];
    float* O = (float*)d_out;

    const size_t bytes_kv = 2 * NELEM * 2;                           //  8 MB
    const size_t bytes_mu = (size_t)S_LEN * S_LEN;                   // 16 MB (u8)
    const size_t bytes_ls = (size_t)NSPLIT * NROWS * 4;              //  1 MB
    const size_t bytes_pa = (size_t)NSPLIT * NROWS * DMODEL * 2;     // 33.5 MB (bf16)

    unsigned short* Ktt = (unsigned short*)d_ws;
    unsigned short* Vtt = Ktt + NELEM;
    unsigned char*  Mu  = (unsigned char*)(Vtt + NELEM);

    const size_t need = bytes_kv + bytes_mu + bytes_ls + bytes_pa;   // ~58.5 MB

    if (ws_size >= need) {
        float* Plsum = (float*)((char*)d_ws + bytes_kv + bytes_mu);
        unsigned short* Pacc = (unsigned short*)((char*)d_ws + bytes_kv + bytes_mu + bytes_ls);
        convert_all<<<10240, 256, 0, stream>>>(K, V, M, Ktt, Vtt, Mu);
        attn_frag<NSPLIT><<<8 * NQT * NSPLIT, 256, 0, stream>>>(
            Q, Ktt, Vtt, Mu, Pacc, Plsum, O);
        reduce_split<NSPLIT><<<(int)(NROWS / 16), 256, 0, stream>>>(Pacc, Plsum, O);
    } else {
        attn_fb<<<512, 256, 0, stream>>>(Q, K, V, M, O);
    }
}

// Round 21
// 89.536 us; speedup vs baseline: 3.9650x; 3.9650x over previous
//
#include <hip/hip_runtime.h>
#include <hip/hip_bf16.h>

#define S_LEN 4096
#define DMODEL 64
#define QBLK 256                            // per block (4 waves x 64 rows)
#define NQT (S_LEN / QBLK)                  // 16 q-tiles
#define KBLK 32
#define NKT (S_LEN / KBLK)                  // 128 k-tiles
#define NSPLIT 8
#define NROWS ((size_t)8 * S_LEN)           // 32768 (b,q) rows
#define NELEM ((size_t)8 * S_LEN * DMODEL)  // per-tensor elements (Q/K/V)
#define TSZ 2048                            // elements per staging sub-tile (4KB bf16)
#define MH 2048                             // mask bytes per (kt,h) sub-tile (u8)
#define QSCALE 0.180336880f                 // 0.125 * log2(e)

typedef __attribute__((ext_vector_type(8))) short bf16x8;
typedef __attribute__((ext_vector_type(4))) float f32x4;
typedef __attribute__((ext_vector_type(4))) unsigned short us4;
typedef __attribute__((ext_vector_type(8))) unsigned short us8;
typedef __attribute__((ext_vector_type(4))) unsigned int u32x4;

// barrier without the vmcnt(0) drain (LDS visibility needs only lgkmcnt)
#define LDS_BARRIER()                                            \
    do {                                                         \
        asm volatile("s_waitcnt lgkmcnt(0)" ::: "memory");       \
        __builtin_amdgcn_s_barrier();                            \
    } while (0)

__device__ __forceinline__ float bf2f(unsigned short u) {
    unsigned int x = ((unsigned int)u) << 16;
    return __builtin_bit_cast(float, x);
}
__device__ __forceinline__ unsigned short f2bf(float f) {
    unsigned int u = __builtin_bit_cast(unsigned int, f);
    u += 0x7FFFu + ((u >> 16) & 1u);   // RNE
    return (unsigned short)(u >> 16);
}
__device__ __forceinline__ unsigned int packbf2(float lo, float hi) {
    __hip_bfloat162 h = __float22bfloat162_rn(float2{lo, hi});
    unsigned int w;
    __builtin_memcpy(&w, &h, sizeof(w));
    return w;
}
// byte i of word w as float (v_cvt_f32_ubyte)
__device__ __forceinline__ float ub(unsigned int w, int i) {
    return (float)((w >> (8 * i)) & 0xFFu);
}
__device__ __forceinline__ bf16x8 cvt8s(const float* __restrict__ p, float c) {
    f32x4 a = *(const f32x4*)p;
    f32x4 b = *(const f32x4*)(p + 4);
    bf16x8 r;
    r[0] = (short)f2bf(a[0] * c); r[1] = (short)f2bf(a[1] * c);
    r[2] = (short)f2bf(a[2] * c); r[3] = (short)f2bf(a[3] * c);
    r[4] = (short)f2bf(b[0] * c); r[5] = (short)f2bf(b[1] * c);
    r[6] = (short)f2bf(b[2] * c); r[7] = (short)f2bf(b[3] * c);
    return r;
}
__device__ __forceinline__ unsigned int q8(float m) {
    return (unsigned int)(m * 255.f + 0.5f);   // m in [0,1)
}

// ---- fused converts. blocks [0,1024): K, [1024,2048): V, [2048,10240): M(u8) ----
__global__ __launch_bounds__(256)
void convert_all(const float* __restrict__ K, const float* __restrict__ V,
                 const float* __restrict__ M,
                 unsigned short* __restrict__ Ktt, unsigned short* __restrict__ Vtt,
                 unsigned char* __restrict__ Mu) {
    const int t = threadIdx.x;
    int bid = blockIdx.x;

    if (bid < 1024) {
        // K -> fragment-major Ktt[b][kt][frag][lane]
        const int b  = bid >> 7;
        const int kt = bid & 127;
        const int l = t & 63, frag = t >> 6;
        const int j = l & 15, g = l >> 4;
        const int row = kt * KBLK + ((frag >> 1) & 1) * 16 + j;
        const int col = (frag & 1) * 32 + g * 8;
        const float* src = K + ((size_t)b * S_LEN + row) * DMODEL + col;
        f32x4 a = *(const f32x4*)src;
        f32x4 c = *(const f32x4*)(src + 4);
        us8 o;
        o[0] = f2bf(a[0]); o[1] = f2bf(a[1]); o[2] = f2bf(a[2]); o[3] = f2bf(a[3]);
        o[4] = f2bf(c[0]); o[5] = f2bf(c[1]); o[6] = f2bf(c[2]); o[7] = f2bf(c[3]);
        *(us8*)(Ktt + ((size_t)(b * NKT + kt)) * TSZ + t * 8) = o;
    } else if (bid < 2048) {
        // V -> fragment-major Vtt[b][kt][dt][lane] (transpose via LDS)
        bid -= 1024;
        __shared__ unsigned short lk[KBLK][68];
        const int b  = bid >> 7;
        const int kt = bid & 127;
        {
            const int key = t >> 3, d0 = (t & 7) * 8;
            const float* src = V + ((size_t)b * S_LEN + kt * KBLK + key) * DMODEL + d0;
            f32x4 a = *(const f32x4*)src;
            f32x4 c = *(const f32x4*)(src + 4);
            lk[key][d0 + 0] = f2bf(a[0]); lk[key][d0 + 1] = f2bf(a[1]);
            lk[key][d0 + 2] = f2bf(a[2]); lk[key][d0 + 3] = f2bf(a[3]);
            lk[key][d0 + 4] = f2bf(c[0]); lk[key][d0 + 5] = f2bf(c[1]);
            lk[key][d0 + 6] = f2bf(c[2]); lk[key][d0 + 7] = f2bf(c[3]);
        }
        __syncthreads();
        {
            const int l = t & 63, dt = t >> 6;
            const int j = l & 15, g = l >> 4;
            us8 o;
            #pragma unroll
            for (int e = 0; e < 8; ++e) {
                const int key = 16 * (e >> 2) + 4 * g + (e & 3);
                o[e] = lk[key][dt * 16 + j];
            }
            *(us8*)(Vtt + ((size_t)(b * NKT + kt)) * TSZ + t * 8) = o;
        }
    } else {
        // M -> per-wave-linear u8 Mu[qt][kt][h=0..3][t*8..]; 255-scale cancels in renorm
        bid -= 2048;                         // [0, 8192)
        const int qt  = bid >> 9;            // 0..15
        const int rem = bid & 511;
        const int kt  = rem >> 2;            // 0..127
        const int h   = rem & 3;             // q-subgroup (16 rows each)
        const int l = t & 63, w = t >> 6;
        const int j = l & 15, g = l >> 4;
        const int row = qt * QBLK + w * 64 + h * 16 + j;
        const float* src = M + ((size_t)row) * S_LEN + kt * KBLK;
        f32x4 a = *(const f32x4*)(src + 4 * g);
        f32x4 c = *(const f32x4*)(src + 16 + 4 * g);
        uint2 o;
        o.x = q8(a[0]) | (q8(a[1]) << 8) | (q8(a[2]) << 16) | (q8(a[3]) << 24);
        o.y = q8(c[0]) | (q8(c[1]) << 8) | (q8(c[2]) << 16) | (q8(c[3]) << 24);
        *(uint2*)(Mu + (((size_t)(qt * NKT + kt)) * 4 + h) * MH + t * 8) = o;
    }
}

// ---- attention: 64 q-rows/wave (4 chains), LDS dbuf, split-K=8, bf16 partials ----
// NOTE: launch_bounds min-waves MUST stay 2 — (256,4) forces VGPR 112->64 and
// spills all accumulators to scratch (round-20 regression: 891 MB scratch WRITE).
template <int SPLITS>
__global__ __launch_bounds__(256, 2)
void attn_frag(const float* __restrict__ Q,
               const unsigned short* __restrict__ Ktt,
               const unsigned short* __restrict__ Vtt,
               const unsigned char* __restrict__ Mu,
               unsigned short* __restrict__ Pacc, float* __restrict__ Plsum,
               float* __restrict__ O) {
    // S: K buf0 [0,2048), K buf1 [2048,4096), V buf0 [4096,6144), V buf1 [6144,8192)
    __shared__ __align__(16) unsigned short S[8192];   // 16 KB

    const int t    = threadIdx.x;
    const int wave = t >> 6;
    const int l    = t & 63;
    const int g    = l >> 4;
    const int j    = l & 15;

    const int bid = blockIdx.x;
    const int b   = bid & 7;             // batch <-> XCD (K/V L2-resident)
    const int qt  = (bid >> 3) & 15;
    const int sp  = (SPLITS > 1) ? (bid >> 7) : 0;
    const int nsteps = NKT / SPLITS;
    const int qrow0 = qt * QBLK + wave * 64 + j;   // chain c: qrow0 + 16*c
    const size_t row0 = (size_t)b * S_LEN + qrow0;

    const float* Qb = Q + (size_t)b * S_LEN * DMODEL;
    bf16x8 qf0[4], qf1[4];
    #pragma unroll
    for (int c = 0; c < 4; ++c) {
        qf0[c] = cvt8s(Qb + (size_t)(qrow0 + 16 * c) * DMODEL + g * 8, QSCALE);
        qf1[c] = cvt8s(Qb + (size_t)(qrow0 + 16 * c) * DMODEL + g * 8 + 32, QSCALE);
    }

    bf16x8 vones;
    #pragma unroll
    for (int e = 0; e < 8; ++e) vones[e] = (short)0x3F80;

    f32x4 acc[4][4];     // [chain][dt]
    f32x4 accl[4];       // [chain]
    #pragma unroll
    for (int c = 0; c < 4; ++c) {
        accl[c] = f32x4{0.f, 0.f, 0.f, 0.f};
        #pragma unroll
        for (int dt = 0; dt < 4; ++dt) acc[c][dt] = f32x4{0.f, 0.f, 0.f, 0.f};
    }

    const int kt0 = sp * nsteps;
    const unsigned short* pk = Ktt + (size_t)(b * NKT + kt0) * TSZ + t * 8;
    const unsigned short* pv = Vtt + (size_t)(b * NKT + kt0) * TSZ + t * 8;
    const unsigned char*  pm = Mu + ((size_t)(qt * NKT + kt0) * 4) * MH + t * 8;

    // ---- prologue: tile kt0 -> buf0; tile kt0+1 -> regs; masks for both ----
    us8 kreg = *(const us8*)pk;
    us8 vreg = *(const us8*)pv;
    uint2 mA[4], mB[4];
    #pragma unroll
    for (int c = 0; c < 4; ++c) mA[c] = *(const uint2*)(pm + c * MH);
    *(us8*)&S[t * 8]        = kreg;
    *(us8*)&S[4096 + t * 8] = vreg;
    kreg = *(const us8*)(pk + TSZ);
    vreg = *(const us8*)(pv + TSZ);
    #pragma unroll
    for (int c = 0; c < 4; ++c) mB[c] = *(const uint2*)(pm + (4 + c) * MH);
    pk += 2 * TSZ; pv += 2 * TSZ; pm += 8 * MH;   // -> tile s+2
    LDS_BARRIER();

    // Prefetch pointers overrun the split range by <=2 tiles at the end; those
    // reads land in the adjacent ws arrays (in-bounds) and are never consumed.
    for (int p = 0; p < nsteps / 2; ++p) {
        #pragma unroll
        for (int u = 0; u < 2; ++u) {
            // 1) stage tile s+1 (in regs) into buf u^1 — linear t*16, conflict-free
            *(us8*)&S[(u ^ 1) * 2048 + t * 8]        = kreg;
            *(us8*)&S[4096 + (u ^ 1) * 2048 + t * 8] = vreg;

            // 2) issue loads for tile s+2
            kreg = *(const us8*)pk; pk += TSZ;
            vreg = *(const us8*)pv; pv += TSZ;

            // 3) compute step s from buf u (static offsets via unroll)
            bf16x8 kf0 = *(const bf16x8*)&S[u * 2048 + 0 * 512 + l * 8];
            bf16x8 kf1 = *(const bf16x8*)&S[u * 2048 + 1 * 512 + l * 8];
            bf16x8 kf2 = *(const bf16x8*)&S[u * 2048 + 2 * 512 + l * 8];
            bf16x8 kf3 = *(const bf16x8*)&S[u * 2048 + 3 * 512 + l * 8];

            bf16x8 pf[4];
            #pragma unroll
            for (int c = 0; c < 4; ++c) {
                f32x4 s0 = {0.f, 0.f, 0.f, 0.f}, s1 = {0.f, 0.f, 0.f, 0.f};
                s0 = __builtin_amdgcn_mfma_f32_16x16x32_bf16(kf0, qf0[c], s0, 0, 0, 0);
                s0 = __builtin_amdgcn_mfma_f32_16x16x32_bf16(kf1, qf1[c], s0, 0, 0, 0);
                s1 = __builtin_amdgcn_mfma_f32_16x16x32_bf16(kf2, qf0[c], s1, 0, 0, 0);
                s1 = __builtin_amdgcn_mfma_f32_16x16x32_bf16(kf3, qf1[c], s1, 0, 0, 0);
                // s0[r]: key kb+4g+r; s1[r]: key kb+16+4g+r; col = qrow0+16c

                const uint2 m = u ? mB[c] : mA[c];
                float e0[4], e1[4];
                #pragma unroll
                for (int r = 0; r < 4; ++r) {
                    e0[r] = __builtin_amdgcn_exp2f(s0[r]) * ub(m.x, r);
                    e1[r] = __builtin_amdgcn_exp2f(s1[r]) * ub(m.y, r);
                }
                u32x4 pw;
                pw[0] = packbf2(e0[0], e0[1]); pw[1] = packbf2(e0[2], e0[3]);
                pw[2] = packbf2(e1[0], e1[1]); pw[3] = packbf2(e1[2], e1[3]);
                pf[c] = __builtin_bit_cast(bf16x8, pw);  // slot e: key kb+16*(e>>2)+4g+(e&3)

                accl[c] = __builtin_amdgcn_mfma_f32_16x16x32_bf16(vones, pf[c], accl[c], 0, 0, 0);
            }

            // 4) reload masks for step s+2 into the same (static) slots
            if (u == 0) {
                #pragma unroll
                for (int c = 0; c < 4; ++c) mA[c] = *(const uint2*)(pm + c * MH);
            } else {
                #pragma unroll
                for (int c = 0; c < 4; ++c) mB[c] = *(const uint2*)(pm + c * MH);
            }
            pm += 4 * MH;

            // 5) PV: each V fragment load feeds all 4 chains (4x amortized)
            #pragma unroll
            for (int dt = 0; dt < 4; ++dt) {
                bf16x8 vf = *(const bf16x8*)&S[4096 + u * 2048 + dt * 512 + l * 8];
                #pragma unroll
                for (int c = 0; c < 4; ++c)
                    acc[c][dt] = __builtin_amdgcn_mfma_f32_16x16x32_bf16(vf, pf[c], acc[c][dt], 0, 0, 0);
            }

            // 6) drain-free barrier
            LDS_BARRIER();
        }
    }

    if (SPLITS > 1) {
        // bf16 partials: rounding cancels in the final normalize (0.3% rel)
        #pragma unroll
        for (int c = 0; c < 4; ++c) {
            const size_t row = row0 + 16 * c;
            if (g == 0) Plsum[(size_t)sp * NROWS + row] = accl[c][0];
            unsigned short* pr = Pacc + ((size_t)sp * NROWS + row) * DMODEL;
            #pragma unroll
            for (int dt = 0; dt < 4; ++dt) {
                us4 o;
                #pragma unroll
                for (int r = 0; r < 4; ++r) o[r] = f2bf(acc[c][dt][r]);
                *(us4*)(pr + dt * 16 + g * 4) = o;
            }
        }
    } else {
        #pragma unroll
        for (int c = 0; c < 4; ++c) {
            const float inv = 1.0f / accl[c][0];
            float* orow = O + (row0 + 16 * c) * DMODEL;
            #pragma unroll
            for (int dt = 0; dt < 4; ++dt) {
                f32x4 o;
                #pragma unroll
                for (int r = 0; r < 4; ++r) o[r] = acc[c][dt][r] * inv;
                *(f32x4*)(orow + dt * 16 + g * 4) = o;
            }
        }
    }
}

// ---- reduce: O = sum_s acc_s(bf16) / sum_s lsum_s ----
template <int SPLITS>
__global__ __launch_bounds__(256)
void reduce_split(const unsigned short* __restrict__ Pacc,
                  const float* __restrict__ Plsum, float* __restrict__ O) {
    const int t = threadIdx.x;
    const size_t rid = (size_t)blockIdx.x * 16 + (t >> 4);
    const int seg = (t & 15) * 4;

    float ls = 0.f;
    f32x4 a = {0.f, 0.f, 0.f, 0.f};
    #pragma unroll
    for (int s = 0; s < SPLITS; ++s) {
        ls += Plsum[(size_t)s * NROWS + rid];
        us4 v = *(const us4*)(Pacc + ((size_t)s * NROWS + rid) * DMODEL + seg);
        a[0] += bf2f(v[0]); a[1] += bf2f(v[1]); a[2] += bf2f(v[2]); a[3] += bf2f(v[3]);
    }
    const float inv = 1.0f / ls;
    f32x4 o = {a[0] * inv, a[1] * inv, a[2] * inv, a[3] * inv};
    *(f32x4*)(O + rid * DMODEL + seg) = o;
}

// ---- no-workspace fallback: direct fp32 loads (validated math, QBLK=64 grid) ----
__global__ __launch_bounds__(256)
void attn_fb(const float* __restrict__ Q, const float* __restrict__ Kf,
             const float* __restrict__ Vf, const float* __restrict__ M,
             float* __restrict__ O) {
    const int t    = threadIdx.x;
    const int wave = t >> 6;
    const int lane = t & 63;
    const int g    = lane >> 4;
    const int j    = lane & 15;
    const int bid  = blockIdx.x;
    const int b    = bid & 7;
    const int qt   = bid >> 3;
    const int qrow = qt * 64 + wave * 16 + j;

    const float* Qb = Q + (size_t)b * S_LEN * DMODEL;
    const bf16x8 qf0 = cvt8s(Qb + (size_t)qrow * DMODEL + g * 8, QSCALE);
    const bf16x8 qf1 = cvt8s(Qb + (size_t)qrow * DMODEL + g * 8 + 32, QSCALE);

    f32x4 acc[4];
    #pragma unroll
    for (int dt = 0; dt < 4; ++dt) acc[dt] = f32x4{0.f, 0.f, 0.f, 0.f};
    float lsum = 0.f;

    const float* Kfb = Kf + (size_t)b * S_LEN * DMODEL;
    const float* Vfb = Vf + (size_t)b * S_LEN * DMODEL;
    const float* mrow = M + (size_t)qrow * S_LEN;

    int kg[8];
    #pragma unroll
    for (int e = 0; e < 8; ++e) kg[e] = 16 * (e >> 2) + 4 * g + (e & 3);

    for (int kt = 0; kt < NKT; ++kt) {
        const int kb = kt * KBLK;
        bf16x8 kf00 = cvt8s(Kfb + (size_t)(kb + j) * DMODEL + g * 8, 1.0f);
        bf16x8 kf01 = cvt8s(Kfb + (size_t)(kb + j) * DMODEL + g * 8 + 32, 1.0f);
        bf16x8 kf10 = cvt8s(Kfb + (size_t)(kb + 16 + j) * DMODEL + g * 8, 1.0f);
        bf16x8 kf11 = cvt8s(Kfb + (size_t)(kb + 16 + j) * DMODEL + g * 8 + 32, 1.0f);

        f32x4 st0 = {0.f, 0.f, 0.f, 0.f};
        f32x4 st1 = {0.f, 0.f, 0.f, 0.f};
        st0 = __builtin_amdgcn_mfma_f32_16x16x32_bf16(kf00, qf0, st0, 0, 0, 0);
        st0 = __builtin_amdgcn_mfma_f32_16x16x32_bf16(kf01, qf1, st0, 0, 0, 0);
        st1 = __builtin_amdgcn_mfma_f32_16x16x32_bf16(kf10, qf0, st1, 0, 0, 0);
        st1 = __builtin_amdgcn_mfma_f32_16x16x32_bf16(kf11, qf1, st1, 0, 0, 0);

        f32x4 m0 = *(const f32x4*)(mrow + kb + g * 4);
        f32x4 m1 = *(const f32x4*)(mrow + kb + 16 + g * 4);

        bf16x8 pf;
        #pragma unroll
        for (int r = 0; r < 4; ++r) {
            float w0 = __builtin_amdgcn_exp2f(st0[r]) * m0[r];
            float w1 = __builtin_amdgcn_exp2f(st1[r]) * m1[r];
            lsum += w0 + w1;
            pf[r]     = (short)f2bf(w0);
            pf[4 + r] = (short)f2bf(w1);
        }

        #pragma unroll
        for (int dt = 0; dt < 4; ++dt) {
            bf16x8 vf;
            #pragma unroll
            for (int e = 0; e < 8; ++e)
                vf[e] = (short)f2bf(Vfb[(size_t)(kb + kg[e]) * DMODEL + dt * 16 + j]);
            acc[dt] = __builtin_amdgcn_mfma_f32_16x16x32_bf16(vf, pf, acc[dt], 0, 0, 0);
        }
    }

    lsum += __shfl_xor(lsum, 16, 64);
    lsum += __shfl_xor(lsum, 32, 64);
    const float inv = 1.0f / lsum;

    float* orow = O + ((size_t)b * S_LEN + qrow) * DMODEL;
    #pragma unroll
    for (int dt = 0; dt < 4; ++dt) {
        f32x4 o;
        #pragma unroll
        for (int r = 0; r < 4; ++r) o[r] = acc[dt][r] * inv;
        *(f32x4*)(orow + dt * 16 + g * 4) = o;
    }
}

extern "C" void kernel_launch(void* const* d_in, const int* in_sizes, int n_in,
                              void* d_out, int out_size, void* d_ws, size_t ws_size,
                              hipStream_t stream) {
    const float* Q = (const float*)d_in[0];
    const float* K = (const float*)d_in[1];
    const float* V = (const float*)d_in[2];
    const float* M = (const float*)d_in[3];
    float* O = (float*)d_out;

    const size_t bytes_kv = 2 * NELEM * 2;                           //  8 MB
    const size_t bytes_mu = (size_t)S_LEN * S_LEN;                   // 16 MB (u8)
    const size_t bytes_ls = (size_t)NSPLIT * NROWS * 4;              //  1 MB
    const size_t bytes_pa = (size_t)NSPLIT * NROWS * DMODEL * 2;     // 33.5 MB (bf16)

    unsigned short* Ktt = (unsigned short*)d_ws;
    unsigned short* Vtt = Ktt + NELEM;
    unsigned char*  Mu  = (unsigned char*)(Vtt + NELEM);

    const size_t need = bytes_kv + bytes_mu + bytes_ls + bytes_pa;   // ~58.5 MB

    if (ws_size >= need) {
        float* Plsum = (float*)((char*)d_ws + bytes_kv + bytes_mu);
        unsigned short* Pacc = (unsigned short*)((char*)d_ws + bytes_kv + bytes_mu + bytes_ls);
        convert_all<<<10240, 256, 0, stream>>>(K, V, M, Ktt, Vtt, Mu);
        attn_frag<NSPLIT><<<8 * NQT * NSPLIT, 256, 0, stream>>>(
            Q, Ktt, Vtt, Mu, Pacc, Plsum, O);
        reduce_split<NSPLIT><<<(int)(NROWS / 16), 256, 0, stream>>>(Pacc, Plsum, O);
    } else {
        attn_fb<<<512, 256, 0, stream>>>(Q, K, V, M, O);
    }
}

// Round 22
// 81.519 us; speedup vs baseline: 4.3549x; 1.0983x over previous
//
#include <hip/hip_runtime.h>
#include <hip/hip_bf16.h>

#define S_LEN 4096
#define DMODEL 64
#define QBLK 256                            // per block (4 waves x 64 rows)
#define NQT (S_LEN / QBLK)                  // 16 q-tiles
#define KBLK 32
#define NKT (S_LEN / KBLK)                  // 128 k-tiles
#define NSPLIT 4
#define NROWS ((size_t)8 * S_LEN)           // 32768 (b,q) rows
#define NELEM ((size_t)8 * S_LEN * DMODEL)  // per-tensor elements (Q/K/V)
#define TSZ 2048                            // elements per staging sub-tile (4KB bf16)
#define MH 2048                             // mask bytes per (kt,h) sub-tile (u8)
#define QSCALE 0.180336880f                 // 0.125 * log2(e)

typedef __attribute__((ext_vector_type(8))) short bf16x8;
typedef __attribute__((ext_vector_type(4))) float f32x4;
typedef __attribute__((ext_vector_type(4))) unsigned short us4;
typedef __attribute__((ext_vector_type(8))) unsigned short us8;
typedef __attribute__((ext_vector_type(4))) unsigned int u32x4;

// barrier without the vmcnt(0) drain (LDS visibility needs only lgkmcnt)
#define LDS_BARRIER()                                            \
    do {                                                         \
        asm volatile("s_waitcnt lgkmcnt(0)" ::: "memory");       \
        __builtin_amdgcn_s_barrier();                            \
    } while (0)

__device__ __forceinline__ float bf2f(unsigned short u) {
    unsigned int x = ((unsigned int)u) << 16;
    return __builtin_bit_cast(float, x);
}
__device__ __forceinline__ unsigned short f2bf(float f) {
    unsigned int u = __builtin_bit_cast(unsigned int, f);
    u += 0x7FFFu + ((u >> 16) & 1u);   // RNE
    return (unsigned short)(u >> 16);
}
__device__ __forceinline__ unsigned int packbf2(float lo, float hi) {
    __hip_bfloat162 h = __float22bfloat162_rn(float2{lo, hi});
    unsigned int w;
    __builtin_memcpy(&w, &h, sizeof(w));
    return w;
}
// byte i of word w as float (v_cvt_f32_ubyte)
__device__ __forceinline__ float ub(unsigned int w, int i) {
    return (float)((w >> (8 * i)) & 0xFFu);
}
__device__ __forceinline__ bf16x8 cvt8s(const float* __restrict__ p, float c) {
    f32x4 a = *(const f32x4*)p;
    f32x4 b = *(const f32x4*)(p + 4);
    bf16x8 r;
    r[0] = (short)f2bf(a[0] * c); r[1] = (short)f2bf(a[1] * c);
    r[2] = (short)f2bf(a[2] * c); r[3] = (short)f2bf(a[3] * c);
    r[4] = (short)f2bf(b[0] * c); r[5] = (short)f2bf(b[1] * c);
    r[6] = (short)f2bf(b[2] * c); r[7] = (short)f2bf(b[3] * c);
    return r;
}
__device__ __forceinline__ unsigned int q8(float m) {
    return (unsigned int)(m * 255.f + 0.5f);   // m in [0,1)
}

// ---- fused converts. blocks [0,1024): K, [1024,2048): V, [2048,10240): M(u8) ----
__global__ __launch_bounds__(256)
void convert_all(const float* __restrict__ K, const float* __restrict__ V,
                 const float* __restrict__ M,
                 unsigned short* __restrict__ Ktt, unsigned short* __restrict__ Vtt,
                 unsigned char* __restrict__ Mu) {
    const int t = threadIdx.x;
    int bid = blockIdx.x;

    if (bid < 1024) {
        // K -> fragment-major Ktt[b][kt][frag][lane]
        const int b  = bid >> 7;
        const int kt = bid & 127;
        const int l = t & 63, frag = t >> 6;
        const int j = l & 15, g = l >> 4;
        const int row = kt * KBLK + ((frag >> 1) & 1) * 16 + j;
        const int col = (frag & 1) * 32 + g * 8;
        const float* src = K + ((size_t)b * S_LEN + row) * DMODEL + col;
        f32x4 a = *(const f32x4*)src;
        f32x4 c = *(const f32x4*)(src + 4);
        us8 o;
        o[0] = f2bf(a[0]); o[1] = f2bf(a[1]); o[2] = f2bf(a[2]); o[3] = f2bf(a[3]);
        o[4] = f2bf(c[0]); o[5] = f2bf(c[1]); o[6] = f2bf(c[2]); o[7] = f2bf(c[3]);
        *(us8*)(Ktt + ((size_t)(b * NKT + kt)) * TSZ + t * 8) = o;
    } else if (bid < 2048) {
        // V -> fragment-major Vtt[b][kt][dt][lane] (transpose via LDS)
        bid -= 1024;
        __shared__ unsigned short lk[KBLK][68];
        const int b  = bid >> 7;
        const int kt = bid & 127;
        {
            const int key = t >> 3, d0 = (t & 7) * 8;
            const float* src = V + ((size_t)b * S_LEN + kt * KBLK + key) * DMODEL + d0;
            f32x4 a = *(const f32x4*)src;
            f32x4 c = *(const f32x4*)(src + 4);
            lk[key][d0 + 0] = f2bf(a[0]); lk[key][d0 + 1] = f2bf(a[1]);
            lk[key][d0 + 2] = f2bf(a[2]); lk[key][d0 + 3] = f2bf(a[3]);
            lk[key][d0 + 4] = f2bf(c[0]); lk[key][d0 + 5] = f2bf(c[1]);
            lk[key][d0 + 6] = f2bf(c[2]); lk[key][d0 + 7] = f2bf(c[3]);
        }
        __syncthreads();
        {
            const int l = t & 63, dt = t >> 6;
            const int j = l & 15, g = l >> 4;
            us8 o;
            #pragma unroll
            for (int e = 0; e < 8; ++e) {
                const int key = 16 * (e >> 2) + 4 * g + (e & 3);
                o[e] = lk[key][dt * 16 + j];
            }
            *(us8*)(Vtt + ((size_t)(b * NKT + kt)) * TSZ + t * 8) = o;
        }
    } else {
        // M -> per-wave-linear u8 Mu[qt][kt][h=0..3][t*8..]; 255-scale cancels in renorm
        bid -= 2048;                         // [0, 8192)
        const int qt  = bid >> 9;            // 0..15
        const int rem = bid & 511;
        const int kt  = rem >> 2;            // 0..127
        const int h   = rem & 3;             // q-subgroup (16 rows each)
        const int l = t & 63, w = t >> 6;
        const int j = l & 15, g = l >> 4;
        const int row = qt * QBLK + w * 64 + h * 16 + j;
        const float* src = M + ((size_t)row) * S_LEN + kt * KBLK;
        f32x4 a = *(const f32x4*)(src + 4 * g);
        f32x4 c = *(const f32x4*)(src + 16 + 4 * g);
        uint2 o;
        o.x = q8(a[0]) | (q8(a[1]) << 8) | (q8(a[2]) << 16) | (q8(a[3]) << 24);
        o.y = q8(c[0]) | (q8(c[1]) << 8) | (q8(c[2]) << 16) | (q8(c[3]) << 24);
        *(uint2*)(Mu + (((size_t)(qt * NKT + kt)) * 4 + h) * MH + t * 8) = o;
    }
}

// ---- attention: 64 q-rows/wave (4 chains), LDS dbuf, split-K=4, bf16 partials ----
// NOTE: launch_bounds min-waves MUST stay 2 — (256,4) forces VGPR 112->64 and
// spills all accumulators to scratch (round-20 regression: 891 MB scratch WRITE).
template <int SPLITS>
__global__ __launch_bounds__(256, 2)
void attn_frag(const float* __restrict__ Q,
               const unsigned short* __restrict__ Ktt,
               const unsigned short* __restrict__ Vtt,
               const unsigned char* __restrict__ Mu,
               unsigned short* __restrict__ Pacc, float* __restrict__ Plsum,
               float* __restrict__ O) {
    // S: K buf0 [0,2048), K buf1 [2048,4096), V buf0 [4096,6144), V buf1 [6144,8192)
    __shared__ __align__(16) unsigned short S[8192];   // 16 KB

    const int t    = threadIdx.x;
    const int wave = t >> 6;
    const int l    = t & 63;
    const int g    = l >> 4;
    const int j    = l & 15;

    const int bid = blockIdx.x;
    const int b   = bid & 7;             // batch <-> XCD (K/V L2-resident)
    const int qt  = (bid >> 3) & 15;
    const int sp  = (SPLITS > 1) ? (bid >> 7) : 0;
    const int nsteps = NKT / SPLITS;
    const int qrow0 = qt * QBLK + wave * 64 + j;   // chain c: qrow0 + 16*c
    const size_t row0 = (size_t)b * S_LEN + qrow0;

    const float* Qb = Q + (size_t)b * S_LEN * DMODEL;
    bf16x8 qf0[4], qf1[4];
    #pragma unroll
    for (int c = 0; c < 4; ++c) {
        qf0[c] = cvt8s(Qb + (size_t)(qrow0 + 16 * c) * DMODEL + g * 8, QSCALE);
        qf1[c] = cvt8s(Qb + (size_t)(qrow0 + 16 * c) * DMODEL + g * 8 + 32, QSCALE);
    }

    bf16x8 vones;
    #pragma unroll
    for (int e = 0; e < 8; ++e) vones[e] = (short)0x3F80;

    f32x4 acc[4][4];     // [chain][dt]
    f32x4 accl[4];       // [chain]
    #pragma unroll
    for (int c = 0; c < 4; ++c) {
        accl[c] = f32x4{0.f, 0.f, 0.f, 0.f};
        #pragma unroll
        for (int dt = 0; dt < 4; ++dt) acc[c][dt] = f32x4{0.f, 0.f, 0.f, 0.f};
    }

    const int kt0 = sp * nsteps;
    const unsigned short* pk = Ktt + (size_t)(b * NKT + kt0) * TSZ + t * 8;
    const unsigned short* pv = Vtt + (size_t)(b * NKT + kt0) * TSZ + t * 8;
    const unsigned char*  pm = Mu + ((size_t)(qt * NKT + kt0) * 4) * MH + t * 8;

    // ---- prologue: tile kt0 -> buf0; tile kt0+1 -> regs; masks for both ----
    us8 kreg = *(const us8*)pk;
    us8 vreg = *(const us8*)pv;
    uint2 mA[4], mB[4];
    #pragma unroll
    for (int c = 0; c < 4; ++c) mA[c] = *(const uint2*)(pm + c * MH);
    *(us8*)&S[t * 8]        = kreg;
    *(us8*)&S[4096 + t * 8] = vreg;
    kreg = *(const us8*)(pk + TSZ);
    vreg = *(const us8*)(pv + TSZ);
    #pragma unroll
    for (int c = 0; c < 4; ++c) mB[c] = *(const uint2*)(pm + (4 + c) * MH);
    pk += 2 * TSZ; pv += 2 * TSZ; pm += 8 * MH;   // -> tile s+2
    LDS_BARRIER();

    // Prefetch pointers overrun the split range by <=2 tiles at the end; those
    // reads land in the adjacent ws arrays (in-bounds) and are never consumed.
    for (int p = 0; p < nsteps / 2; ++p) {
        #pragma unroll
        for (int u = 0; u < 2; ++u) {
            // 1) stage tile s+1 (in regs) into buf u^1 — linear t*16, conflict-free
            *(us8*)&S[(u ^ 1) * 2048 + t * 8]        = kreg;
            *(us8*)&S[4096 + (u ^ 1) * 2048 + t * 8] = vreg;

            // 2) issue loads for tile s+2
            kreg = *(const us8*)pk; pk += TSZ;
            vreg = *(const us8*)pv; pv += TSZ;

            // 3) compute step s from buf u (static offsets via unroll)
            bf16x8 kf0 = *(const bf16x8*)&S[u * 2048 + 0 * 512 + l * 8];
            bf16x8 kf1 = *(const bf16x8*)&S[u * 2048 + 1 * 512 + l * 8];
            bf16x8 kf2 = *(const bf16x8*)&S[u * 2048 + 2 * 512 + l * 8];
            bf16x8 kf3 = *(const bf16x8*)&S[u * 2048 + 3 * 512 + l * 8];

            bf16x8 pf[4];
            #pragma unroll
            for (int c = 0; c < 4; ++c) {
                f32x4 s0 = {0.f, 0.f, 0.f, 0.f}, s1 = {0.f, 0.f, 0.f, 0.f};
                s0 = __builtin_amdgcn_mfma_f32_16x16x32_bf16(kf0, qf0[c], s0, 0, 0, 0);
                s0 = __builtin_amdgcn_mfma_f32_16x16x32_bf16(kf1, qf1[c], s0, 0, 0, 0);
                s1 = __builtin_amdgcn_mfma_f32_16x16x32_bf16(kf2, qf0[c], s1, 0, 0, 0);
                s1 = __builtin_amdgcn_mfma_f32_16x16x32_bf16(kf3, qf1[c], s1, 0, 0, 0);
                // s0[r]: key kb+4g+r; s1[r]: key kb+16+4g+r; col = qrow0+16c

                const uint2 m = u ? mB[c] : mA[c];
                float e0[4], e1[4];
                #pragma unroll
                for (int r = 0; r < 4; ++r) {
                    e0[r] = __builtin_amdgcn_exp2f(s0[r]) * ub(m.x, r);
                    e1[r] = __builtin_amdgcn_exp2f(s1[r]) * ub(m.y, r);
                }
                u32x4 pw;
                pw[0] = packbf2(e0[0], e0[1]); pw[1] = packbf2(e0[2], e0[3]);
                pw[2] = packbf2(e1[0], e1[1]); pw[3] = packbf2(e1[2], e1[3]);
                pf[c] = __builtin_bit_cast(bf16x8, pw);  // slot e: key kb+16*(e>>2)+4g+(e&3)

                accl[c] = __builtin_amdgcn_mfma_f32_16x16x32_bf16(vones, pf[c], accl[c], 0, 0, 0);
            }

            // 4) reload masks for step s+2 into the same (static) slots
            if (u == 0) {
                #pragma unroll
                for (int c = 0; c < 4; ++c) mA[c] = *(const uint2*)(pm + c * MH);
            } else {
                #pragma unroll
                for (int c = 0; c < 4; ++c) mB[c] = *(const uint2*)(pm + c * MH);
            }
            pm += 4 * MH;

            // 5) PV: each V fragment load feeds all 4 chains (4x amortized)
            #pragma unroll
            for (int dt = 0; dt < 4; ++dt) {
                bf16x8 vf = *(const bf16x8*)&S[4096 + u * 2048 + dt * 512 + l * 8];
                #pragma unroll
                for (int c = 0; c < 4; ++c)
                    acc[c][dt] = __builtin_amdgcn_mfma_f32_16x16x32_bf16(vf, pf[c], acc[c][dt], 0, 0, 0);
            }

            // 6) drain-free barrier
            LDS_BARRIER();
        }
    }

    if (SPLITS > 1) {
        // bf16 partials: rounding cancels in the final normalize (verified: absmax
        // unchanged vs f32 partials in round 21)
        #pragma unroll
        for (int c = 0; c < 4; ++c) {
            const size_t row = row0 + 16 * c;
            if (g == 0) Plsum[(size_t)sp * NROWS + row] = accl[c][0];
            unsigned short* pr = Pacc + ((size_t)sp * NROWS + row) * DMODEL;
            #pragma unroll
            for (int dt = 0; dt < 4; ++dt) {
                us4 o;
                #pragma unroll
                for (int r = 0; r < 4; ++r) o[r] = f2bf(acc[c][dt][r]);
                *(us4*)(pr + dt * 16 + g * 4) = o;
            }
        }
    } else {
        #pragma unroll
        for (int c = 0; c < 4; ++c) {
            const float inv = 1.0f / accl[c][0];
            float* orow = O + (row0 + 16 * c) * DMODEL;
            #pragma unroll
            for (int dt = 0; dt < 4; ++dt) {
                f32x4 o;
                #pragma unroll
                for (int r = 0; r < 4; ++r) o[r] = acc[c][dt][r] * inv;
                *(f32x4*)(orow + dt * 16 + g * 4) = o;
            }
        }
    }
}

// ---- reduce: O = sum_s acc_s(bf16) / sum_s lsum_s ----
template <int SPLITS>
__global__ __launch_bounds__(256)
void reduce_split(const unsigned short* __restrict__ Pacc,
                  const float* __restrict__ Plsum, float* __restrict__ O) {
    const int t = threadIdx.x;
    const size_t rid = (size_t)blockIdx.x * 16 + (t >> 4);
    const int seg = (t & 15) * 4;

    float ls = 0.f;
    f32x4 a = {0.f, 0.f, 0.f, 0.f};
    #pragma unroll
    for (int s = 0; s < SPLITS; ++s) {
        ls += Plsum[(size_t)s * NROWS + rid];
        us4 v = *(const us4*)(Pacc + ((size_t)s * NROWS + rid) * DMODEL + seg);
        a[0] += bf2f(v[0]); a[1] += bf2f(v[1]); a[2] += bf2f(v[2]); a[3] += bf2f(v[3]);
    }
    const float inv = 1.0f / ls;
    f32x4 o = {a[0] * inv, a[1] * inv, a[2] * inv, a[3] * inv};
    *(f32x4*)(O + rid * DMODEL + seg) = o;
}

// ---- no-workspace fallback: direct fp32 loads (validated math, QBLK=64 grid) ----
__global__ __launch_bounds__(256)
void attn_fb(const float* __restrict__ Q, const float* __restrict__ Kf,
             const float* __restrict__ Vf, const float* __restrict__ M,
             float* __restrict__ O) {
    const int t    = threadIdx.x;
    const int wave = t >> 6;
    const int lane = t & 63;
    const int g    = lane >> 4;
    const int j    = lane & 15;
    const int bid  = blockIdx.x;
    const int b    = bid & 7;
    const int qt   = bid >> 3;
    const int qrow = qt * 64 + wave * 16 + j;

    const float* Qb = Q + (size_t)b * S_LEN * DMODEL;
    const bf16x8 qf0 = cvt8s(Qb + (size_t)qrow * DMODEL + g * 8, QSCALE);
    const bf16x8 qf1 = cvt8s(Qb + (size_t)qrow * DMODEL + g * 8 + 32, QSCALE);

    f32x4 acc[4];
    #pragma unroll
    for (int dt = 0; dt < 4; ++dt) acc[dt] = f32x4{0.f, 0.f, 0.f, 0.f};
    float lsum = 0.f;

    const float* Kfb = Kf + (size_t)b * S_LEN * DMODEL;
    const float* Vfb = Vf + (size_t)b * S_LEN * DMODEL;
    const float* mrow = M + (size_t)qrow * S_LEN;

    int kg[8];
    #pragma unroll
    for (int e = 0; e < 8; ++e) kg[e] = 16 * (e >> 2) + 4 * g + (e & 3);

    for (int kt = 0; kt < NKT; ++kt) {
        const int kb = kt * KBLK;
        bf16x8 kf00 = cvt8s(Kfb + (size_t)(kb + j) * DMODEL + g * 8, 1.0f);
        bf16x8 kf01 = cvt8s(Kfb + (size_t)(kb + j) * DMODEL + g * 8 + 32, 1.0f);
        bf16x8 kf10 = cvt8s(Kfb + (size_t)(kb + 16 + j) * DMODEL + g * 8, 1.0f);
        bf16x8 kf11 = cvt8s(Kfb + (size_t)(kb + 16 + j) * DMODEL + g * 8 + 32, 1.0f);

        f32x4 st0 = {0.f, 0.f, 0.f, 0.f};
        f32x4 st1 = {0.f, 0.f, 0.f, 0.f};
        st0 = __builtin_amdgcn_mfma_f32_16x16x32_bf16(kf00, qf0, st0, 0, 0, 0);
        st0 = __builtin_amdgcn_mfma_f32_16x16x32_bf16(kf01, qf1, st0, 0, 0, 0);
        st1 = __builtin_amdgcn_mfma_f32_16x16x32_bf16(kf10, qf0, st1, 0, 0, 0);
        st1 = __builtin_amdgcn_mfma_f32_16x16x32_bf16(kf11, qf1, st1, 0, 0, 0);

        f32x4 m0 = *(const f32x4*)(mrow + kb + g * 4);
        f32x4 m1 = *(const f32x4*)(mrow + kb + 16 + g * 4);

        bf16x8 pf;
        #pragma unroll
        for (int r = 0; r < 4; ++r) {
            float w0 = __builtin_amdgcn_exp2f(st0[r]) * m0[r];
            float w1 = __builtin_amdgcn_exp2f(st1[r]) * m1[r];
            lsum += w0 + w1;
            pf[r]     = (short)f2bf(w0);
            pf[4 + r] = (short)f2bf(w1);
        }

        #pragma unroll
        for (int dt = 0; dt < 4; ++dt) {
            bf16x8 vf;
            #pragma unroll
            for (int e = 0; e < 8; ++e)
                vf[e] = (short)f2bf(Vfb[(size_t)(kb + kg[e]) * DMODEL + dt * 16 + j]);
            acc[dt] = __builtin_amdgcn_mfma_f32_16x16x32_bf16(vf, pf, acc[dt], 0, 0, 0);
        }
    }

    lsum += __shfl_xor(lsum, 16, 64);
    lsum += __shfl_xor(lsum, 32, 64);
    const float inv = 1.0f / lsum;

    float* orow = O + ((size_t)b * S_LEN + qrow) * DMODEL;
    #pragma unroll
    for (int dt = 0; dt < 4; ++dt) {
        f32x4 o;
        #pragma unroll
        for (int r = 0; r < 4; ++r) o[r] = acc[dt][r] * inv;
        *(f32x4*)(orow + dt * 16 + g * 4) = o;
    }
}

extern "C" void kernel_launch(void* const* d_in, const int* in_sizes, int n_in,
                              void* d_out, int out_size, void* d_ws, size_t ws_size,
                              hipStream_t stream) {
    const float* Q = (const float*)d_in[0];
    const float* K = (const float*)d_in[1];
    const float* V = (const float*)d_in[2];
    const float* M = (const float*)d_in[3];
    float* O = (float*)d_out;

    const size_t bytes_kv = 2 * NELEM * 2;                           //  8 MB
    const size_t bytes_mu = (size_t)S_LEN * S_LEN;                   // 16 MB (u8)
    const size_t bytes_ls = (size_t)NSPLIT * NROWS * 4;              //  0.5 MB
    const size_t bytes_pa = (size_t)NSPLIT * NROWS * DMODEL * 2;     // 16.75 MB (bf16)

    unsigned short* Ktt = (unsigned short*)d_ws;
    unsigned short* Vtt = Ktt + NELEM;
    unsigned char*  Mu  = (unsigned char*)(Vtt + NELEM);

    const size_t need = bytes_kv + bytes_mu + bytes_ls + bytes_pa;   // ~41 MB

    if (ws_size >= need) {
        float* Plsum = (float*)((char*)d_ws + bytes_kv + bytes_mu);
        unsigned short* Pacc = (unsigned short*)((char*)d_ws + bytes_kv + bytes_mu + bytes_ls);
        convert_all<<<10240, 256, 0, stream>>>(K, V, M, Ktt, Vtt, Mu);
        attn_frag<NSPLIT><<<8 * NQT * NSPLIT, 256, 0, stream>>>(
            Q, Ktt, Vtt, Mu, Pacc, Plsum, O);
        reduce_split<NSPLIT><<<(int)(NROWS / 16), 256, 0, stream>>>(Pacc, Plsum, O);
    } else {
        attn_fb<<<512, 256, 0, stream>>>(Q, K, V, M, O);
    }
}